// Round 7
// baseline (248.707 us; speedup 1.0000x reference)
//
#include <hip/hip_runtime.h>

#define FD 128
// deg pass: packed u16 cells, 2 nodes/word, 64 KB LDS
#define CHD 32768
#define NSLD 64
// S pass: u32 cells, 64 KB LDS; NSLS==32 is load-bearing (lane<->slice map in reduce_x)
#define CHS 16384
#define NSLS 32
#define RXB 1024              // reduce_x blocks: 4/CU -> 32 waves/CU for latency hiding
#define RXT 512               // reduce_x threads
#define QSCALE 16777216.0f    // 2^24
#define QINV   5.9604644775390625e-8f

__device__ __forceinline__ unsigned quant_w(int dp1) {
    return (unsigned)(rsqrtf((float)dp1) * QSCALE + 0.5f);
}

// Wave-level dtype probe: sample up to 128 odd u32 words. For an int32 array the
// odd words are full node-id values (zero only if that id is 0, P ~ (1/n)^128);
// for an int64 array they are high halves, all zero. Ballot -> wave-uniform.
__device__ __forceinline__ bool detect_is32_wave(const unsigned int* w, long long nwords) {
    const int lane = threadIdx.x & 63;
    const long long i0 = 2 * lane + 1, i1 = 2 * (lane + 64) + 1;
    unsigned acc = 0;
    if (i0 < nwords) acc |= w[i0];
    if (i1 < nwords) acc |= w[i1];
    return __ballot(acc != 0u) != 0ull;
}

// load 4 consecutive edge indices (elements [off+i .. off+i+4)) from i32/i64 buffer
__device__ __forceinline__ int4 ld_e4(const void* ei, bool is32, long long off, long long i) {
    if (is32) return *reinterpret_cast<const int4*>((const int*)ei + off + i);
    const long long* p = (const long long*)ei + off + i;
    longlong2 a = *reinterpret_cast<const longlong2*>(p);
    longlong2 b = *reinterpret_cast<const longlong2*>(p + 2);
    return make_int4((int)a.x, (int)a.y, (int)b.x, (int)b.y);
}
__device__ __forceinline__ int ld_e1(const void* ei, bool is32, long long idx) {
    return is32 ? ((const int*)ei)[idx] : (int)((const long long*)ei)[idx];
}

// ---- 1: deg histogram over dst, packed u16 LDS cells; also zeroes the done-counter ----
__global__ __launch_bounds__(512) void hist_deg_kernel(
        const void* __restrict__ ei, unsigned int* __restrict__ psD,
        unsigned int* __restrict__ counter, long long E, long long SL, int nch) {
    __shared__ unsigned int hist[CHD / 2];
    const int tid = threadIdx.x;
    if (blockIdx.x == 0 && tid == 0) *counter = 0u;   // consumed 3 kernels later
    const bool is32 = detect_is32_wave((const unsigned int*)ei, 2 * E);
    const int b = blockIdx.x, c = b % nch, j = b / nch;
    const int lo = c * CHD;
    for (int i = tid; i < CHD / 2; i += 512) hist[i] = 0u;
    __syncthreads();
    const long long e0 = (long long)j * SL;
    long long e1 = e0 + SL; if (e1 > E) e1 = E; if (e1 < e0) e1 = e0;
    const long long e1v = e0 + ((e1 - e0) & ~3LL);
    for (long long i = e0 + (long long)tid * 4; i < e1v; i += 2048) {
        int4 d = ld_e4(ei, is32, E, i);
        unsigned u0 = (unsigned)(d.x - lo), u1 = (unsigned)(d.y - lo);
        unsigned u2 = (unsigned)(d.z - lo), u3 = (unsigned)(d.w - lo);
        if (u0 < CHD) atomicAdd(&hist[u0 >> 1], 1u << ((u0 & 1) * 16));
        if (u1 < CHD) atomicAdd(&hist[u1 >> 1], 1u << ((u1 & 1) * 16));
        if (u2 < CHD) atomicAdd(&hist[u2 >> 1], 1u << ((u2 & 1) * 16));
        if (u3 < CHD) atomicAdd(&hist[u3 >> 1], 1u << ((u3 & 1) * 16));
    }
    { long long it = e1v + tid;
      if (it < e1) { unsigned u = (unsigned)(ld_e1(ei, is32, E + it) - lo);
                     if (u < CHD) atomicAdd(&hist[u >> 1], 1u << ((u & 1) * 16)); } }
    __syncthreads();
    unsigned int* o = psD + (size_t)b * (CHD / 2);
    for (int w = tid; w < CHD / 2; w += 512) o[w] = hist[w];
}

// ---- 2: reduce deg partials ----
__global__ void deg_reduce_kernel(const unsigned int* __restrict__ psD,
                                  int* __restrict__ deg, long long n, int nch) {
    const long long tw = blockIdx.x * (long long)blockDim.x + threadIdx.x;
    if (tw >= (long long)nch * (CHD / 2)) return;
    const int cc = (int)(tw / (CHD / 2));
    const int w  = (int)(tw % (CHD / 2));
    unsigned s0 = 0, s1 = 0;
    for (int j = 0; j < NSLD; ++j) {
        unsigned v = psD[((size_t)j * nch + cc) * (CHD / 2) + w];
        s0 += v & 0xffffu; s1 += v >> 16;
    }
    const long long v0 = (long long)cc * CHD + 2 * w;
    if (v0 < n) deg[v0] = (int)s0;
    if (v0 + 1 < n) deg[v0 + 1] = (int)s1;
}

// ---- 3: weighted src histogram; deg gather + quantization folded in ----
__global__ __launch_bounds__(512) void hist_s_kernel(
        const void* __restrict__ ei, const int* __restrict__ deg,
        unsigned int* __restrict__ psS, long long E, long long SL, int nch) {
    __shared__ unsigned int hist[CHS];
    const int tid = threadIdx.x;
    const bool is32 = detect_is32_wave((const unsigned int*)ei, 2 * E);
    const int b = blockIdx.x, c = b % nch, j = b / nch;
    const int lo = c * CHS;
    for (int i = tid; i < CHS; i += 512) hist[i] = 0u;
    __syncthreads();
    const long long e0 = (long long)j * SL;
    long long e1 = e0 + SL; if (e1 > E) e1 = E; if (e1 < e0) e1 = e0;
    const long long e1v = e0 + ((e1 - e0) & ~3LL);
    for (long long i = e0 + (long long)tid * 4; i < e1v; i += 2048) {
        int4 s = ld_e4(ei, is32, 0, i);
        int4 d = ld_e4(ei, is32, E, i);
        unsigned u0 = (unsigned)(s.x - lo), u1 = (unsigned)(s.y - lo);
        unsigned u2 = (unsigned)(s.z - lo), u3 = (unsigned)(s.w - lo);
        if (u0 < CHS) atomicAdd(&hist[u0], quant_w(deg[d.x] + 1));
        if (u1 < CHS) atomicAdd(&hist[u1], quant_w(deg[d.y] + 1));
        if (u2 < CHS) atomicAdd(&hist[u2], quant_w(deg[d.z] + 1));
        if (u3 < CHS) atomicAdd(&hist[u3], quant_w(deg[d.w] + 1));
    }
    { long long it = e1v + tid;
      if (it < e1) { unsigned u = (unsigned)(ld_e1(ei, is32, it) - lo);
                     if (u < CHS) atomicAdd(&hist[u], quant_w(deg[ld_e1(ei, is32, E + it)] + 1)); } }
    __syncthreads();
    unsigned int* o = psS + (size_t)b * CHS;
    for (int w = tid; w < CHS; w += 512) o[w] = hist[w];
}

// ---- 4: fused coef-on-the-fly + x reduction + last-block colsum/matvec ----
__global__ __launch_bounds__(RXT) void reduce_x_final_kernel(
        const float* __restrict__ x, const int* __restrict__ deg,
        const unsigned int* __restrict__ psS, const float* __restrict__ Wm,
        const float* __restrict__ bias, float* __restrict__ P,
        unsigned int* __restrict__ counter, float* __restrict__ out,
        long long n, int nchs) {
    __shared__ float4 sm4[RXT];
    const int tid = threadIdx.x;
    const int lane = tid & 31;          // slice index AND float4-column within row
    const int grp = tid >> 5;           // 16 groups of 32
    float4 a = make_float4(0.f, 0.f, 0.f, 0.f);
    const long long tot = n * (FD / 4);
    for (long long i = blockIdx.x * (long long)RXT + tid; i < tot;
         i += (long long)RXB * RXT) {
        const long long v = i >> 5;     // whole 32-lane group shares one node v
        // S[v]*2^24 = exact u32 butterfly over the 32 slice partials (lane L reads slice L)
        const int cc = (int)(v / CHS);
        const int u  = (int)(v % CHS);
        unsigned s = psS[((size_t)lane * nchs + cc) * CHS + u];
        #pragma unroll
        for (int m = 1; m < 32; m <<= 1)
            s += (unsigned)__shfl_xor((int)s, m, 32);
        const float dg = (float)(deg[v] + 1);
        const float di = rsqrtf(dg);
        const float coef = di * ((float)s * QINV) + 1.0f / dg;
        const float4 xv = reinterpret_cast<const float4*>(x)[i];
        a.x += coef * xv.x; a.y += coef * xv.y; a.z += coef * xv.z; a.w += coef * xv.w;
    }
    sm4[tid] = a;
    __syncthreads();
    for (int s2 = 8; s2 > 0; s2 >>= 1) {
        if (grp < s2) {
            float4 o = sm4[(grp + s2) * 32 + lane];
            float4 m = sm4[tid];
            m.x += o.x; m.y += o.y; m.z += o.z; m.w += o.w;
            sm4[tid] = m;
        }
        __syncthreads();
    }
    if (tid < 32) reinterpret_cast<float4*>(P)[blockIdx.x * 32 + tid] = sm4[tid];
    __threadfence();                      // release P row (device scope)
    __shared__ unsigned last;
    if (tid == 0) {
        unsigned old = atomicAdd(counter, 1u);
        last = (old == RXB - 1) ? 1u : 0u;
        if (last) atomicExch(counter, 0u);   // reset for next replay
    }
    __syncthreads();
    if (last == 0u) return;               // block-uniform
    __threadfence();
    // tail: tcol[k] = sum_j P[j][k]; u64 agent-scope atomic loads (cross-XCD safe)
    __shared__ float2 part2[RXT];
    const int k2 = tid & 63;              // column pair (0..63)
    const int q  = tid >> 6;              // 0..7, RXB/8 rows each
    float2 ps = make_float2(0.f, 0.f);
    for (int j = q * (RXB / 8); j < (q + 1) * (RXB / 8); ++j) {
        unsigned long long uv = __hip_atomic_load(
            (const unsigned long long*)&P[(size_t)j * FD + 2 * k2],
            __ATOMIC_RELAXED, __HIP_MEMORY_SCOPE_AGENT);
        union { unsigned long long u; float2 f; } cv; cv.u = uv;
        ps.x += cv.f.x; ps.y += cv.f.y;
    }
    part2[tid] = ps;
    __syncthreads();
    for (int s2 = 4; s2 > 0; s2 >>= 1) {
        if (q < s2) {
            float2 o = part2[(q + s2) * 64 + k2];
            float2 m = part2[tid];
            m.x += o.x; m.y += o.y;
            part2[tid] = m;
        }
        __syncthreads();
    }
    __shared__ float tcol[FD];
    if (tid < 64) { tcol[2 * tid] = part2[tid].x; tcol[2 * tid + 1] = part2[tid].y; }
    __syncthreads();
    if (tid < FD) {
        float acc = 0.f;
        #pragma unroll 16
        for (int kk = 0; kk < FD; ++kk) acc += Wm[tid * FD + kk] * tcol[kk];
        out[tid] = acc + (float)n * bias[tid];
    }
}

// ================= fallback (R2-proven global-atomic path) =================
__global__ void deg_fb(const void* __restrict__ ei, int* __restrict__ deg, long long E) {
    const bool is32 = detect_is32_wave((const unsigned int*)ei, 2 * E);
    const long long st = (long long)gridDim.x * blockDim.x;
    long long i = blockIdx.x * (long long)blockDim.x + threadIdx.x;
    for (; i < E; i += st) atomicAdd(&deg[ld_e1(ei, is32, E + i)], 1);
}

__global__ void srcsum_fb(const void* __restrict__ ei, const int* __restrict__ deg,
                          unsigned int* __restrict__ Sq, long long E) {
    const bool is32 = detect_is32_wave((const unsigned int*)ei, 2 * E);
    const long long st = (long long)gridDim.x * blockDim.x;
    long long i = blockIdx.x * (long long)blockDim.x + threadIdx.x;
    for (; i < E; i += st)
        atomicAdd(&Sq[ld_e1(ei, is32, i)], quant_w(deg[ld_e1(ei, is32, E + i)] + 1));
}

__global__ void coef_fb(unsigned int* __restrict__ Sq, const int* __restrict__ deg,
                        long long n) {
    const long long v = blockIdx.x * (long long)blockDim.x + threadIdx.x;
    if (v >= n) return;
    unsigned s = Sq[v];
    float dg = (float)(deg[v] + 1);
    float di = rsqrtf(dg);
    ((float*)Sq)[v] = di * ((float)s * QINV) + 1.0f / dg;
}

__global__ void redx_fb(const float* __restrict__ x, const float* __restrict__ coef,
                        float* __restrict__ t, long long n) {
    __shared__ float sm[FD];
    for (int f = threadIdx.x; f < FD; f += blockDim.x) sm[f] = 0.f;
    __syncthreads();
    const long long tot = n * (FD / 4);
    const long long st = (long long)gridDim.x * blockDim.x;
    const int lane = threadIdx.x & 31;
    float4 a = make_float4(0.f, 0.f, 0.f, 0.f);
    for (long long i = blockIdx.x * (long long)blockDim.x + threadIdx.x; i < tot; i += st) {
        float cf = coef[i >> 5];
        float4 xv = reinterpret_cast<const float4*>(x)[i];
        a.x += cf * xv.x; a.y += cf * xv.y; a.z += cf * xv.z; a.w += cf * xv.w;
    }
    atomicAdd(&sm[lane * 4 + 0], a.x);
    atomicAdd(&sm[lane * 4 + 1], a.y);
    atomicAdd(&sm[lane * 4 + 2], a.z);
    atomicAdd(&sm[lane * 4 + 3], a.w);
    __syncthreads();
    for (int f = threadIdx.x; f < FD; f += blockDim.x) atomicAdd(&t[f], sm[f]);
}

__global__ void final_fb(const float* __restrict__ Wm, const float* __restrict__ bias,
                         const float* __restrict__ t, float* __restrict__ out, float nn) {
    __shared__ float ts[FD];
    int f = threadIdx.x;
    if (f < FD) ts[f] = t[f];
    __syncthreads();
    if (f < FD) {
        float a0 = 0.f;
        #pragma unroll 16
        for (int k = 0; k < FD; ++k) a0 += Wm[f * FD + k] * ts[k];
        out[f] = a0 + nn * bias[f];
    }
}

// ==============================================================================
extern "C" void kernel_launch(void* const* d_in, const int* in_sizes, int n_in,
                              void* d_out, int out_size, void* d_ws, size_t ws_size,
                              hipStream_t stream) {
    const float* x    = (const float*)d_in[0];
    const float* W    = (const float*)d_in[1];
    const float* bias = (const float*)d_in[2];
    const void*  ei   = d_in[3];
    float* out = (float*)d_out;
    const long long n = in_sizes[0] / FD;            // 100000
    const long long E = (long long)in_sizes[3] / 2;  // 1600000

    const int NCHD = (int)((n + CHD - 1) / CHD);     // 4
    const int NCHS = (int)((n + CHS - 1) / CHS);     // 7
    const long long SLD = ((E + NSLD - 1) / NSLD + 3) & ~3LL;   // 25000
    const long long SLS = ((E + NSLS - 1) / NSLS + 3) & ~3LL;   // 50000

    char* ws = (char*)d_ws;
    size_t off = 0;
    auto take = [&](size_t bytes) { size_t r = off; off += (bytes + 255) & ~(size_t)255; return r; };
    unsigned int* psD     = (unsigned int*)(ws + take((size_t)NCHD * NSLD * (CHD / 2) * 4));
    unsigned int* psS     = (unsigned int*)(ws + take((size_t)NCHS * NSLS * CHS * 4));
    int*          deg     = (int*)(ws + take((size_t)n * 4));
    float*        P       = (float*)(ws + take((size_t)RXB * FD * 4));
    unsigned int* counter = (unsigned int*)(ws + take(256));
    const size_t need = off;

    const bool main_ok = (ws_size >= need) && ((E & 3) == 0) && (E >= 512) &&
                         (SLD < 65536);

    if (main_ok) {
        hist_deg_kernel<<<NCHD * NSLD, 512, 0, stream>>>(ei, psD, counter, E, SLD, NCHD);
        {
            long long nw = (long long)NCHD * (CHD / 2);
            deg_reduce_kernel<<<(int)((nw + 255) / 256), 256, 0, stream>>>(psD, deg, n, NCHD);
        }
        hist_s_kernel<<<NCHS * NSLS, 512, 0, stream>>>(ei, deg, psS, E, SLS, NCHS);
        reduce_x_final_kernel<<<RXB, RXT, 0, stream>>>(x, deg, psS, W, bias, P,
                                                       counter, out, n, NCHS);
    } else {
        int*          degF = (int*)ws;
        unsigned int* Sq   = (unsigned int*)(ws + (size_t)n * 4);
        float*        tF   = (float*)(ws + (size_t)n * 8);
        hipMemsetAsync(ws, 0, (size_t)n * 8 + 512, stream);
        deg_fb<<<1600, 256, 0, stream>>>(ei, degF, E);
        srcsum_fb<<<1600, 256, 0, stream>>>(ei, degF, Sq, E);
        coef_fb<<<(int)((n + 255) / 256), 256, 0, stream>>>(Sq, degF, n);
        redx_fb<<<2048, 256, 0, stream>>>(x, (const float*)Sq, tF, n);
        final_fb<<<1, FD, 0, stream>>>(W, bias, tF, out, (float)n);
    }
}

// Round 8
// 164.008 us; speedup vs baseline: 1.5164x; 1.5164x over previous
//
#include <hip/hip_runtime.h>

#define FD 128
// deg pass: packed u16 cells, 2 nodes/word, 64 KB LDS
#define CHD 32768
#define NSLD 64
// S pass: u32 cells, 64 KB LDS
#define CHS 16384
#define NSLS 32
#define RXB 512               // reduce_x blocks: 2/CU -> 16 waves/CU
#define RXT 512               // reduce_x threads
#define QSCALE 16777216.0f    // 2^24
#define QINV   5.9604644775390625e-8f

__device__ __forceinline__ unsigned quant_w(int dp1) {
    return (unsigned)(rsqrtf((float)dp1) * QSCALE + 0.5f);
}

// Wave-level dtype probe: sample up to 128 odd u32 words. For an int32 array the
// odd words are full node-id values (zero only if that id is 0, P ~ (1/n)^128);
// for an int64 array they are high halves, all zero. Ballot -> wave-uniform.
__device__ __forceinline__ bool detect_is32_wave(const unsigned int* w, long long nwords) {
    const int lane = threadIdx.x & 63;
    const long long i0 = 2 * lane + 1, i1 = 2 * (lane + 64) + 1;
    unsigned acc = 0;
    if (i0 < nwords) acc |= w[i0];
    if (i1 < nwords) acc |= w[i1];
    return __ballot(acc != 0u) != 0ull;
}

// load 4 consecutive edge indices (elements [off+i .. off+i+4)) from i32/i64 buffer
__device__ __forceinline__ int4 ld_e4(const void* ei, bool is32, long long off, long long i) {
    if (is32) return *reinterpret_cast<const int4*>((const int*)ei + off + i);
    const long long* p = (const long long*)ei + off + i;
    longlong2 a = *reinterpret_cast<const longlong2*>(p);
    longlong2 b = *reinterpret_cast<const longlong2*>(p + 2);
    return make_int4((int)a.x, (int)a.y, (int)b.x, (int)b.y);
}
__device__ __forceinline__ int ld_e1(const void* ei, bool is32, long long idx) {
    return is32 ? ((const int*)ei)[idx] : (int)((const long long*)ei)[idx];
}

// ---- 1: deg histogram over dst, packed u16 LDS cells; also zeroes the done-counter ----
__global__ __launch_bounds__(512) void hist_deg_kernel(
        const void* __restrict__ ei, unsigned int* __restrict__ psD,
        unsigned int* __restrict__ counter, long long E, long long SL, int nch) {
    __shared__ unsigned int hist[CHD / 2];
    const int tid = threadIdx.x;
    if (blockIdx.x == 0 && tid == 0) *counter = 0u;   // consumed 4 kernels later
    const bool is32 = detect_is32_wave((const unsigned int*)ei, 2 * E);
    const int b = blockIdx.x, c = b % nch, j = b / nch;
    const int lo = c * CHD;
    for (int i = tid; i < CHD / 2; i += 512) hist[i] = 0u;
    __syncthreads();
    const long long e0 = (long long)j * SL;
    long long e1 = e0 + SL; if (e1 > E) e1 = E; if (e1 < e0) e1 = e0;
    const long long e1v = e0 + ((e1 - e0) & ~3LL);
    for (long long i = e0 + (long long)tid * 4; i < e1v; i += 2048) {
        int4 d = ld_e4(ei, is32, E, i);
        unsigned u0 = (unsigned)(d.x - lo), u1 = (unsigned)(d.y - lo);
        unsigned u2 = (unsigned)(d.z - lo), u3 = (unsigned)(d.w - lo);
        if (u0 < CHD) atomicAdd(&hist[u0 >> 1], 1u << ((u0 & 1) * 16));
        if (u1 < CHD) atomicAdd(&hist[u1 >> 1], 1u << ((u1 & 1) * 16));
        if (u2 < CHD) atomicAdd(&hist[u2 >> 1], 1u << ((u2 & 1) * 16));
        if (u3 < CHD) atomicAdd(&hist[u3 >> 1], 1u << ((u3 & 1) * 16));
    }
    { long long it = e1v + tid;
      if (it < e1) { unsigned u = (unsigned)(ld_e1(ei, is32, E + it) - lo);
                     if (u < CHD) atomicAdd(&hist[u >> 1], 1u << ((u & 1) * 16)); } }
    __syncthreads();
    unsigned int* o = psD + (size_t)b * (CHD / 2);
    for (int w = tid; w < CHD / 2; w += 512) o[w] = hist[w];
}

// ---- 2: reduce deg partials ----
__global__ void deg_reduce_kernel(const unsigned int* __restrict__ psD,
                                  int* __restrict__ deg, long long n, int nch) {
    const long long tw = blockIdx.x * (long long)blockDim.x + threadIdx.x;
    if (tw >= (long long)nch * (CHD / 2)) return;
    const int cc = (int)(tw / (CHD / 2));
    const int w  = (int)(tw % (CHD / 2));
    unsigned s0 = 0, s1 = 0;
    for (int j = 0; j < NSLD; ++j) {
        unsigned v = psD[((size_t)j * nch + cc) * (CHD / 2) + w];
        s0 += v & 0xffffu; s1 += v >> 16;
    }
    const long long v0 = (long long)cc * CHD + 2 * w;
    if (v0 < n) deg[v0] = (int)s0;
    if (v0 + 1 < n) deg[v0 + 1] = (int)s1;
}

// ---- 3: weighted src histogram; deg gather + quantization folded in ----
__global__ __launch_bounds__(512) void hist_s_kernel(
        const void* __restrict__ ei, const int* __restrict__ deg,
        unsigned int* __restrict__ psS, long long E, long long SL, int nch) {
    __shared__ unsigned int hist[CHS];
    const int tid = threadIdx.x;
    const bool is32 = detect_is32_wave((const unsigned int*)ei, 2 * E);
    const int b = blockIdx.x, c = b % nch, j = b / nch;
    const int lo = c * CHS;
    for (int i = tid; i < CHS; i += 512) hist[i] = 0u;
    __syncthreads();
    const long long e0 = (long long)j * SL;
    long long e1 = e0 + SL; if (e1 > E) e1 = E; if (e1 < e0) e1 = e0;
    const long long e1v = e0 + ((e1 - e0) & ~3LL);
    for (long long i = e0 + (long long)tid * 4; i < e1v; i += 2048) {
        int4 s = ld_e4(ei, is32, 0, i);
        int4 d = ld_e4(ei, is32, E, i);
        unsigned u0 = (unsigned)(s.x - lo), u1 = (unsigned)(s.y - lo);
        unsigned u2 = (unsigned)(s.z - lo), u3 = (unsigned)(s.w - lo);
        if (u0 < CHS) atomicAdd(&hist[u0], quant_w(deg[d.x] + 1));
        if (u1 < CHS) atomicAdd(&hist[u1], quant_w(deg[d.y] + 1));
        if (u2 < CHS) atomicAdd(&hist[u2], quant_w(deg[d.z] + 1));
        if (u3 < CHS) atomicAdd(&hist[u3], quant_w(deg[d.w] + 1));
    }
    { long long it = e1v + tid;
      if (it < e1) { unsigned u = (unsigned)(ld_e1(ei, is32, it) - lo);
                     if (u < CHS) atomicAdd(&hist[u], quant_w(deg[ld_e1(ei, is32, E + it)] + 1)); } }
    __syncthreads();
    unsigned int* o = psS + (size_t)b * CHS;
    for (int w = tid; w < CHS; w += 512) o[w] = hist[w];
}

// ---- 4: reduce S partials -> coef[v] (coalesced psS reads: consecutive v -> consecutive u) ----
__global__ void coef_reduce_kernel(const unsigned int* __restrict__ psS,
                                   const int* __restrict__ deg,
                                   float* __restrict__ coef, long long n, int nch) {
    const long long v = blockIdx.x * (long long)blockDim.x + threadIdx.x;
    if (v >= n) return;
    const int cc = (int)(v / CHS);
    const int u  = (int)(v % CHS);
    unsigned s = 0;
    #pragma unroll 8
    for (int jj = 0; jj < NSLS; ++jj)
        s += psS[((size_t)jj * nch + cc) * CHS + u];
    const float dg = (float)(deg[v] + 1);
    const float di = rsqrtf(dg);
    coef[v] = di * ((float)s * QINV) + 1.0f / dg;
}

// ---- 5: x reduction (streaming, broadcast coef) + last-block colsum/matvec ----
__global__ __launch_bounds__(RXT) void reduce_x_final_kernel(
        const float* __restrict__ x, const float* __restrict__ coef,
        const float* __restrict__ Wm, const float* __restrict__ bias,
        float* __restrict__ P, unsigned int* __restrict__ counter,
        float* __restrict__ out, long long n) {
    __shared__ float4 sm4[RXT];
    const int tid = threadIdx.x;
    const int lane = tid & 31;          // float4-column within a node row
    const int grp = tid >> 5;           // 16 groups of 32
    float4 a = make_float4(0.f, 0.f, 0.f, 0.f);
    const long long tot = n * (FD / 4);
    for (long long i = blockIdx.x * (long long)RXT + tid; i < tot;
         i += (long long)RXB * RXT) {
        const float cf = coef[i >> 5];  // group-broadcast, L2-resident
        const float4 xv = reinterpret_cast<const float4*>(x)[i];
        a.x += cf * xv.x; a.y += cf * xv.y; a.z += cf * xv.z; a.w += cf * xv.w;
    }
    sm4[tid] = a;
    __syncthreads();
    for (int s2 = 8; s2 > 0; s2 >>= 1) {
        if (grp < s2) {
            float4 o = sm4[(grp + s2) * 32 + lane];
            float4 m = sm4[tid];
            m.x += o.x; m.y += o.y; m.z += o.z; m.w += o.w;
            sm4[tid] = m;
        }
        __syncthreads();
    }
    if (tid < 32) reinterpret_cast<float4*>(P)[blockIdx.x * 32 + tid] = sm4[tid];
    __threadfence();                      // release P row (device scope)
    __shared__ unsigned last;
    if (tid == 0) {
        unsigned old = atomicAdd(counter, 1u);
        last = (old == RXB - 1) ? 1u : 0u;
        if (last) atomicExch(counter, 0u);   // reset for next replay
    }
    __syncthreads();
    if (last == 0u) return;               // block-uniform
    __threadfence();
    // tail: tcol[k] = sum_j P[j][k]; u64 agent-scope atomic loads (cross-XCD safe)
    __shared__ float2 part2[RXT];
    const int k2 = tid & 63;              // column pair (0..63)
    const int q  = tid >> 6;              // 0..7, RXB/8 rows each
    float2 ps = make_float2(0.f, 0.f);
    for (int j = q * (RXB / 8); j < (q + 1) * (RXB / 8); ++j) {
        unsigned long long uv = __hip_atomic_load(
            (const unsigned long long*)&P[(size_t)j * FD + 2 * k2],
            __ATOMIC_RELAXED, __HIP_MEMORY_SCOPE_AGENT);
        union { unsigned long long u; float2 f; } cv; cv.u = uv;
        ps.x += cv.f.x; ps.y += cv.f.y;
    }
    part2[tid] = ps;
    __syncthreads();
    for (int s2 = 4; s2 > 0; s2 >>= 1) {
        if (q < s2) {
            float2 o = part2[(q + s2) * 64 + k2];
            float2 m = part2[tid];
            m.x += o.x; m.y += o.y;
            part2[tid] = m;
        }
        __syncthreads();
    }
    __shared__ float tcol[FD];
    if (tid < 64) { tcol[2 * tid] = part2[tid].x; tcol[2 * tid + 1] = part2[tid].y; }
    __syncthreads();
    if (tid < FD) {
        float acc = 0.f;
        #pragma unroll 16
        for (int kk = 0; kk < FD; ++kk) acc += Wm[tid * FD + kk] * tcol[kk];
        out[tid] = acc + (float)n * bias[tid];
    }
}

// ================= fallback (R2-proven global-atomic path) =================
__global__ void deg_fb(const void* __restrict__ ei, int* __restrict__ deg, long long E) {
    const bool is32 = detect_is32_wave((const unsigned int*)ei, 2 * E);
    const long long st = (long long)gridDim.x * blockDim.x;
    long long i = blockIdx.x * (long long)blockDim.x + threadIdx.x;
    for (; i < E; i += st) atomicAdd(&deg[ld_e1(ei, is32, E + i)], 1);
}

__global__ void srcsum_fb(const void* __restrict__ ei, const int* __restrict__ deg,
                          unsigned int* __restrict__ Sq, long long E) {
    const bool is32 = detect_is32_wave((const unsigned int*)ei, 2 * E);
    const long long st = (long long)gridDim.x * blockDim.x;
    long long i = blockIdx.x * (long long)blockDim.x + threadIdx.x;
    for (; i < E; i += st)
        atomicAdd(&Sq[ld_e1(ei, is32, i)], quant_w(deg[ld_e1(ei, is32, E + i)] + 1));
}

__global__ void coef_fb(unsigned int* __restrict__ Sq, const int* __restrict__ deg,
                        long long n) {
    const long long v = blockIdx.x * (long long)blockDim.x + threadIdx.x;
    if (v >= n) return;
    unsigned s = Sq[v];
    float dg = (float)(deg[v] + 1);
    float di = rsqrtf(dg);
    ((float*)Sq)[v] = di * ((float)s * QINV) + 1.0f / dg;
}

__global__ void redx_fb(const float* __restrict__ x, const float* __restrict__ coef,
                        float* __restrict__ t, long long n) {
    __shared__ float sm[FD];
    for (int f = threadIdx.x; f < FD; f += blockDim.x) sm[f] = 0.f;
    __syncthreads();
    const long long tot = n * (FD / 4);
    const long long st = (long long)gridDim.x * blockDim.x;
    const int lane = threadIdx.x & 31;
    float4 a = make_float4(0.f, 0.f, 0.f, 0.f);
    for (long long i = blockIdx.x * (long long)blockDim.x + threadIdx.x; i < tot; i += st) {
        float cf = coef[i >> 5];
        float4 xv = reinterpret_cast<const float4*>(x)[i];
        a.x += cf * xv.x; a.y += cf * xv.y; a.z += cf * xv.z; a.w += cf * xv.w;
    }
    atomicAdd(&sm[lane * 4 + 0], a.x);
    atomicAdd(&sm[lane * 4 + 1], a.y);
    atomicAdd(&sm[lane * 4 + 2], a.z);
    atomicAdd(&sm[lane * 4 + 3], a.w);
    __syncthreads();
    for (int f = threadIdx.x; f < FD; f += blockDim.x) atomicAdd(&t[f], sm[f]);
}

__global__ void final_fb(const float* __restrict__ Wm, const float* __restrict__ bias,
                         const float* __restrict__ t, float* __restrict__ out, float nn) {
    __shared__ float ts[FD];
    int f = threadIdx.x;
    if (f < FD) ts[f] = t[f];
    __syncthreads();
    if (f < FD) {
        float a0 = 0.f;
        #pragma unroll 16
        for (int k = 0; k < FD; ++k) a0 += Wm[f * FD + k] * ts[k];
        out[f] = a0 + nn * bias[f];
    }
}

// ==============================================================================
extern "C" void kernel_launch(void* const* d_in, const int* in_sizes, int n_in,
                              void* d_out, int out_size, void* d_ws, size_t ws_size,
                              hipStream_t stream) {
    const float* x    = (const float*)d_in[0];
    const float* W    = (const float*)d_in[1];
    const float* bias = (const float*)d_in[2];
    const void*  ei   = d_in[3];
    float* out = (float*)d_out;
    const long long n = in_sizes[0] / FD;            // 100000
    const long long E = (long long)in_sizes[3] / 2;  // 1600000

    const int NCHD = (int)((n + CHD - 1) / CHD);     // 4
    const int NCHS = (int)((n + CHS - 1) / CHS);     // 7
    const long long SLD = ((E + NSLD - 1) / NSLD + 3) & ~3LL;   // 25000
    const long long SLS = ((E + NSLS - 1) / NSLS + 3) & ~3LL;   // 50000

    char* ws = (char*)d_ws;
    size_t off = 0;
    auto take = [&](size_t bytes) { size_t r = off; off += (bytes + 255) & ~(size_t)255; return r; };
    unsigned int* psD     = (unsigned int*)(ws + take((size_t)NCHD * NSLD * (CHD / 2) * 4));
    unsigned int* psS     = (unsigned int*)(ws + take((size_t)NCHS * NSLS * CHS * 4));
    int*          deg     = (int*)(ws + take((size_t)n * 4));
    float*        coef    = (float*)(ws + take((size_t)n * 4));
    float*        P       = (float*)(ws + take((size_t)RXB * FD * 4));
    unsigned int* counter = (unsigned int*)(ws + take(256));
    const size_t need = off;

    const bool main_ok = (ws_size >= need) && ((E & 3) == 0) && (E >= 512) &&
                         (SLD < 65536);

    if (main_ok) {
        hist_deg_kernel<<<NCHD * NSLD, 512, 0, stream>>>(ei, psD, counter, E, SLD, NCHD);
        {
            long long nw = (long long)NCHD * (CHD / 2);
            deg_reduce_kernel<<<(int)((nw + 255) / 256), 256, 0, stream>>>(psD, deg, n, NCHD);
        }
        hist_s_kernel<<<NCHS * NSLS, 512, 0, stream>>>(ei, deg, psS, E, SLS, NCHS);
        coef_reduce_kernel<<<(int)((n + 255) / 256), 256, 0, stream>>>(psS, deg, coef, n, NCHS);
        reduce_x_final_kernel<<<RXB, RXT, 0, stream>>>(x, coef, W, bias, P,
                                                       counter, out, n);
    } else {
        int*          degF = (int*)ws;
        unsigned int* Sq   = (unsigned int*)(ws + (size_t)n * 4);
        float*        tF   = (float*)(ws + (size_t)n * 8);
        hipMemsetAsync(ws, 0, (size_t)n * 8 + 512, stream);
        deg_fb<<<1600, 256, 0, stream>>>(ei, degF, E);
        srcsum_fb<<<1600, 256, 0, stream>>>(ei, degF, Sq, E);
        coef_fb<<<(int)((n + 255) / 256), 256, 0, stream>>>(Sq, degF, n);
        redx_fb<<<2048, 256, 0, stream>>>(x, (const float*)Sq, tF, n);
        final_fb<<<1, FD, 0, stream>>>(W, bias, tF, out, (float)n);
    }
}

// Round 9
// 87.388 us; speedup vs baseline: 2.8460x; 1.8768x over previous
//
#include <hip/hip_runtime.h>

#define FD 128
// deg pass: packed u16 cells, 2 nodes/word, 64 KB LDS
#define CHD 32768
#define NSLD 64
// S pass: u32 cells, 64 KB LDS
#define CHS 16384
#define NSLS 32
#define RXB 512               // reduce_x blocks (R5-proven config)
#define QSCALE 16777216.0f    // 2^24
#define QINV   5.9604644775390625e-8f

__device__ __forceinline__ unsigned quant_w(int dp1) {
    return (unsigned)(rsqrtf((float)dp1) * QSCALE + 0.5f);
}

// Wave-level dtype probe: sample up to 128 odd u32 words. For an int32 array the
// odd words are full node-id values (zero only if that id is 0, P ~ (1/n)^128);
// for an int64 array they are high halves, all zero. Ballot -> wave-uniform.
__device__ __forceinline__ bool detect_is32_wave(const unsigned int* w, long long nwords) {
    const int lane = threadIdx.x & 63;
    const long long i0 = 2 * lane + 1, i1 = 2 * (lane + 64) + 1;
    unsigned acc = 0;
    if (i0 < nwords) acc |= w[i0];
    if (i1 < nwords) acc |= w[i1];
    return __ballot(acc != 0u) != 0ull;
}

// load 4 consecutive edge indices (elements [off+i .. off+i+4)) from i32/i64 buffer
__device__ __forceinline__ int4 ld_e4(const void* ei, bool is32, long long off, long long i) {
    if (is32) return *reinterpret_cast<const int4*>((const int*)ei + off + i);
    const long long* p = (const long long*)ei + off + i;
    longlong2 a = *reinterpret_cast<const longlong2*>(p);
    longlong2 b = *reinterpret_cast<const longlong2*>(p + 2);
    return make_int4((int)a.x, (int)a.y, (int)b.x, (int)b.y);
}
__device__ __forceinline__ int ld_e1(const void* ei, bool is32, long long idx) {
    return is32 ? ((const int*)ei)[idx] : (int)((const long long*)ei)[idx];
}

// ---- 1: deg histogram over dst, packed u16 LDS cells ----
__global__ __launch_bounds__(512) void hist_deg_kernel(
        const void* __restrict__ ei, unsigned int* __restrict__ psD,
        long long E, long long SL, int nch) {
    __shared__ unsigned int hist[CHD / 2];
    const int tid = threadIdx.x;
    const bool is32 = detect_is32_wave((const unsigned int*)ei, 2 * E);
    const int b = blockIdx.x, c = b % nch, j = b / nch;
    const int lo = c * CHD;
    for (int i = tid; i < CHD / 2; i += 512) hist[i] = 0u;
    __syncthreads();
    const long long e0 = (long long)j * SL;
    long long e1 = e0 + SL; if (e1 > E) e1 = E; if (e1 < e0) e1 = e0;
    const long long e1v = e0 + ((e1 - e0) & ~3LL);
    for (long long i = e0 + (long long)tid * 4; i < e1v; i += 2048) {
        int4 d = ld_e4(ei, is32, E, i);
        unsigned u0 = (unsigned)(d.x - lo), u1 = (unsigned)(d.y - lo);
        unsigned u2 = (unsigned)(d.z - lo), u3 = (unsigned)(d.w - lo);
        if (u0 < CHD) atomicAdd(&hist[u0 >> 1], 1u << ((u0 & 1) * 16));
        if (u1 < CHD) atomicAdd(&hist[u1 >> 1], 1u << ((u1 & 1) * 16));
        if (u2 < CHD) atomicAdd(&hist[u2 >> 1], 1u << ((u2 & 1) * 16));
        if (u3 < CHD) atomicAdd(&hist[u3 >> 1], 1u << ((u3 & 1) * 16));
    }
    { long long it = e1v + tid;
      if (it < e1) { unsigned u = (unsigned)(ld_e1(ei, is32, E + it) - lo);
                     if (u < CHD) atomicAdd(&hist[u >> 1], 1u << ((u & 1) * 16)); } }
    __syncthreads();
    unsigned int* o = psD + (size_t)b * (CHD / 2);
    for (int w = tid; w < CHD / 2; w += 512) o[w] = hist[w];
}

// ---- 2: reduce deg partials ----
__global__ void deg_reduce_kernel(const unsigned int* __restrict__ psD,
                                  int* __restrict__ deg, long long n, int nch) {
    const long long tw = blockIdx.x * (long long)blockDim.x + threadIdx.x;
    if (tw >= (long long)nch * (CHD / 2)) return;
    const int cc = (int)(tw / (CHD / 2));
    const int w  = (int)(tw % (CHD / 2));
    unsigned s0 = 0, s1 = 0;
    for (int j = 0; j < NSLD; ++j) {
        unsigned v = psD[((size_t)j * nch + cc) * (CHD / 2) + w];
        s0 += v & 0xffffu; s1 += v >> 16;
    }
    const long long v0 = (long long)cc * CHD + 2 * w;
    if (v0 < n) deg[v0] = (int)s0;
    if (v0 + 1 < n) deg[v0 + 1] = (int)s1;
}

// ---- 3: weighted src histogram; deg gather + quantization folded in ----
__global__ __launch_bounds__(512) void hist_s_kernel(
        const void* __restrict__ ei, const int* __restrict__ deg,
        unsigned int* __restrict__ psS, long long E, long long SL, int nch) {
    __shared__ unsigned int hist[CHS];
    const int tid = threadIdx.x;
    const bool is32 = detect_is32_wave((const unsigned int*)ei, 2 * E);
    const int b = blockIdx.x, c = b % nch, j = b / nch;
    const int lo = c * CHS;
    for (int i = tid; i < CHS; i += 512) hist[i] = 0u;
    __syncthreads();
    const long long e0 = (long long)j * SL;
    long long e1 = e0 + SL; if (e1 > E) e1 = E; if (e1 < e0) e1 = e0;
    const long long e1v = e0 + ((e1 - e0) & ~3LL);
    for (long long i = e0 + (long long)tid * 4; i < e1v; i += 2048) {
        int4 s = ld_e4(ei, is32, 0, i);
        int4 d = ld_e4(ei, is32, E, i);
        unsigned u0 = (unsigned)(s.x - lo), u1 = (unsigned)(s.y - lo);
        unsigned u2 = (unsigned)(s.z - lo), u3 = (unsigned)(s.w - lo);
        if (u0 < CHS) atomicAdd(&hist[u0], quant_w(deg[d.x] + 1));
        if (u1 < CHS) atomicAdd(&hist[u1], quant_w(deg[d.y] + 1));
        if (u2 < CHS) atomicAdd(&hist[u2], quant_w(deg[d.z] + 1));
        if (u3 < CHS) atomicAdd(&hist[u3], quant_w(deg[d.w] + 1));
    }
    { long long it = e1v + tid;
      if (it < e1) { unsigned u = (unsigned)(ld_e1(ei, is32, it) - lo);
                     if (u < CHS) atomicAdd(&hist[u], quant_w(deg[ld_e1(ei, is32, E + it)] + 1)); } }
    __syncthreads();
    unsigned int* o = psS + (size_t)b * CHS;
    for (int w = tid; w < CHS; w += 512) o[w] = hist[w];
}

// ---- 4: reduce S partials -> coef[v] (coalesced psS reads) ----
__global__ void coef_reduce_kernel(const unsigned int* __restrict__ psS,
                                   const int* __restrict__ deg,
                                   float* __restrict__ coef, long long n, int nch) {
    const long long v = blockIdx.x * (long long)blockDim.x + threadIdx.x;
    if (v >= n) return;
    const int cc = (int)(v / CHS);
    const int u  = (int)(v % CHS);
    unsigned s = 0;
    #pragma unroll 8
    for (int jj = 0; jj < NSLS; ++jj)
        s += psS[((size_t)jj * nch + cc) * CHS + u];
    const float dg = (float)(deg[v] + 1);
    const float di = rsqrtf(dg);
    coef[v] = di * ((float)s * QINV) + 1.0f / dg;
}

// ---- 5: t-partials P[b][k] (deterministic, NO fence/counter — R5-proven) ----
__global__ __launch_bounds__(256) void reduce_x_kernel(
        const float* __restrict__ x, const float* __restrict__ coef,
        float* __restrict__ P, long long n) {
    __shared__ float4 sm4[256];
    const int tid = threadIdx.x;
    float4 a = make_float4(0.f, 0.f, 0.f, 0.f);
    const long long tot = n * (FD / 4);
    for (long long i = blockIdx.x * 256LL + tid; i < tot; i += (long long)RXB * 256) {
        float cf = coef[i >> 5];
        float4 xv = reinterpret_cast<const float4*>(x)[i];
        a.x += cf * xv.x; a.y += cf * xv.y; a.z += cf * xv.z; a.w += cf * xv.w;
    }
    const int lane = tid & 31, grp = tid >> 5;   // 8 groups of 32
    sm4[grp * 32 + lane] = a;
    __syncthreads();
    for (int s2 = 4; s2 > 0; s2 >>= 1) {
        if (grp < s2) {
            float4 o = sm4[(grp + s2) * 32 + lane];
            float4 m = sm4[grp * 32 + lane];
            m.x += o.x; m.y += o.y; m.z += o.z; m.w += o.w;
            sm4[grp * 32 + lane] = m;
        }
        __syncthreads();
    }
    if (tid < 32) reinterpret_cast<float4*>(P)[blockIdx.x * 32 + tid] = sm4[tid];
}

// ---- 6: fused colsum + W-matvec: out[f] = sum_j sum_k W[f,k]*P[j,k] + n*bias[f] ----
__global__ __launch_bounds__(256) void colsum_final_kernel(
        const float* __restrict__ P, const float* __restrict__ Wm,
        const float* __restrict__ bias, float* __restrict__ out, float nn) {
    __shared__ float wrow[FD];
    __shared__ float red[256];
    const int f = blockIdx.x, tid = threadIdx.x;
    if (tid < FD) wrow[tid] = Wm[f * FD + tid];
    __syncthreads();
    float part = 0.f;
    for (int j = tid; j < RXB; j += 256) {
        const float4* Pj = reinterpret_cast<const float4*>(P + (size_t)j * FD);
        #pragma unroll
        for (int k = 0; k < FD / 4; ++k) {
            float4 p = Pj[k];
            part += wrow[4 * k] * p.x + wrow[4 * k + 1] * p.y +
                    wrow[4 * k + 2] * p.z + wrow[4 * k + 3] * p.w;
        }
    }
    red[tid] = part;
    __syncthreads();
    for (int s2 = 128; s2 > 0; s2 >>= 1) {
        if (tid < s2) red[tid] += red[tid + s2];
        __syncthreads();
    }
    if (tid == 0) out[f] = red[0] + nn * bias[f];
}

// ================= fallback (R2-proven global-atomic path) =================
__global__ void deg_fb(const void* __restrict__ ei, int* __restrict__ deg, long long E) {
    const bool is32 = detect_is32_wave((const unsigned int*)ei, 2 * E);
    const long long st = (long long)gridDim.x * blockDim.x;
    long long i = blockIdx.x * (long long)blockDim.x + threadIdx.x;
    for (; i < E; i += st) atomicAdd(&deg[ld_e1(ei, is32, E + i)], 1);
}

__global__ void srcsum_fb(const void* __restrict__ ei, const int* __restrict__ deg,
                          unsigned int* __restrict__ Sq, long long E) {
    const bool is32 = detect_is32_wave((const unsigned int*)ei, 2 * E);
    const long long st = (long long)gridDim.x * blockDim.x;
    long long i = blockIdx.x * (long long)blockDim.x + threadIdx.x;
    for (; i < E; i += st)
        atomicAdd(&Sq[ld_e1(ei, is32, i)], quant_w(deg[ld_e1(ei, is32, E + i)] + 1));
}

__global__ void coef_fb(unsigned int* __restrict__ Sq, const int* __restrict__ deg,
                        long long n) {
    const long long v = blockIdx.x * (long long)blockDim.x + threadIdx.x;
    if (v >= n) return;
    unsigned s = Sq[v];
    float dg = (float)(deg[v] + 1);
    float di = rsqrtf(dg);
    ((float*)Sq)[v] = di * ((float)s * QINV) + 1.0f / dg;
}

__global__ void redx_fb(const float* __restrict__ x, const float* __restrict__ coef,
                        float* __restrict__ t, long long n) {
    __shared__ float sm[FD];
    for (int f = threadIdx.x; f < FD; f += blockDim.x) sm[f] = 0.f;
    __syncthreads();
    const long long tot = n * (FD / 4);
    const long long st = (long long)gridDim.x * blockDim.x;
    const int lane = threadIdx.x & 31;
    float4 a = make_float4(0.f, 0.f, 0.f, 0.f);
    for (long long i = blockIdx.x * (long long)blockDim.x + threadIdx.x; i < tot; i += st) {
        float cf = coef[i >> 5];
        float4 xv = reinterpret_cast<const float4*>(x)[i];
        a.x += cf * xv.x; a.y += cf * xv.y; a.z += cf * xv.z; a.w += cf * xv.w;
    }
    atomicAdd(&sm[lane * 4 + 0], a.x);
    atomicAdd(&sm[lane * 4 + 1], a.y);
    atomicAdd(&sm[lane * 4 + 2], a.z);
    atomicAdd(&sm[lane * 4 + 3], a.w);
    __syncthreads();
    for (int f = threadIdx.x; f < FD; f += blockDim.x) atomicAdd(&t[f], sm[f]);
}

__global__ void final_fb(const float* __restrict__ Wm, const float* __restrict__ bias,
                         const float* __restrict__ t, float* __restrict__ out, float nn) {
    __shared__ float ts[FD];
    int f = threadIdx.x;
    if (f < FD) ts[f] = t[f];
    __syncthreads();
    if (f < FD) {
        float a0 = 0.f;
        #pragma unroll 16
        for (int k = 0; k < FD; ++k) a0 += Wm[f * FD + k] * ts[k];
        out[f] = a0 + nn * bias[f];
    }
}

// ==============================================================================
extern "C" void kernel_launch(void* const* d_in, const int* in_sizes, int n_in,
                              void* d_out, int out_size, void* d_ws, size_t ws_size,
                              hipStream_t stream) {
    const float* x    = (const float*)d_in[0];
    const float* W    = (const float*)d_in[1];
    const float* bias = (const float*)d_in[2];
    const void*  ei   = d_in[3];
    float* out = (float*)d_out;
    const long long n = in_sizes[0] / FD;            // 100000
    const long long E = (long long)in_sizes[3] / 2;  // 1600000

    const int NCHD = (int)((n + CHD - 1) / CHD);     // 4
    const int NCHS = (int)((n + CHS - 1) / CHS);     // 7
    const long long SLD = ((E + NSLD - 1) / NSLD + 3) & ~3LL;   // 25000
    const long long SLS = ((E + NSLS - 1) / NSLS + 3) & ~3LL;   // 50000

    char* ws = (char*)d_ws;
    size_t off = 0;
    auto take = [&](size_t bytes) { size_t r = off; off += (bytes + 255) & ~(size_t)255; return r; };
    unsigned int* psD  = (unsigned int*)(ws + take((size_t)NCHD * NSLD * (CHD / 2) * 4));
    unsigned int* psS  = (unsigned int*)(ws + take((size_t)NCHS * NSLS * CHS * 4));
    int*          deg  = (int*)(ws + take((size_t)n * 4));
    float*        coef = (float*)(ws + take((size_t)n * 4));
    float*        P    = (float*)(ws + take((size_t)RXB * FD * 4));
    const size_t need = off;

    const bool main_ok = (ws_size >= need) && ((E & 3) == 0) && (E >= 512) &&
                         (SLD < 65536);

    if (main_ok) {
        hist_deg_kernel<<<NCHD * NSLD, 512, 0, stream>>>(ei, psD, E, SLD, NCHD);
        {
            long long nw = (long long)NCHD * (CHD / 2);
            deg_reduce_kernel<<<(int)((nw + 255) / 256), 256, 0, stream>>>(psD, deg, n, NCHD);
        }
        hist_s_kernel<<<NCHS * NSLS, 512, 0, stream>>>(ei, deg, psS, E, SLS, NCHS);
        coef_reduce_kernel<<<(int)((n + 255) / 256), 256, 0, stream>>>(psS, deg, coef, n, NCHS);
        reduce_x_kernel<<<RXB, 256, 0, stream>>>(x, coef, P, n);
        colsum_final_kernel<<<FD, 256, 0, stream>>>(P, W, bias, out, (float)n);
    } else {
        int*          degF = (int*)ws;
        unsigned int* Sq   = (unsigned int*)(ws + (size_t)n * 4);
        float*        tF   = (float*)(ws + (size_t)n * 8);
        hipMemsetAsync(ws, 0, (size_t)n * 8 + 512, stream);
        deg_fb<<<1600, 256, 0, stream>>>(ei, degF, E);
        srcsum_fb<<<1600, 256, 0, stream>>>(ei, degF, Sq, E);
        coef_fb<<<(int)((n + 255) / 256), 256, 0, stream>>>(Sq, degF, n);
        redx_fb<<<2048, 256, 0, stream>>>(x, (const float*)Sq, tF, n);
        final_fb<<<1, FD, 0, stream>>>(W, bias, tF, out, (float)n);
    }
}

// Round 10
// 77.781 us; speedup vs baseline: 3.1975x; 1.1235x over previous
//
#include <hip/hip_runtime.h>

#define FD 128
// deg pass: packed u16 cells, 2 nodes/word, 64 KB LDS
#define CHD 32768
#define NSLD 64
// S pass: u32 cells, 64 KB LDS
#define CHS 16384
#define NSLS 64
#define RXB 512               // reduce_x blocks (R5-proven config)
#define QSCALE 16777216.0f    // 2^24 (fallback path)
#define QINV   5.9604644775390625e-8f
#define QSCALE2 32768.0f      // 2^15 (u16 qw path)
#define QINV2  3.0517578125e-5f

__device__ __forceinline__ unsigned quant_w(int dp1) {
    return (unsigned)(rsqrtf((float)dp1) * QSCALE + 0.5f);
}
__device__ __forceinline__ unsigned short quant_w16(int dp1) {
    return (unsigned short)(rsqrtf((float)dp1) * QSCALE2 + 0.5f);
}

// Wave-level dtype probe: sample up to 128 odd u32 words. For an int32 array the
// odd words are full node-id values (zero only if that id is 0, P ~ (1/n)^128);
// for an int64 array they are high halves, all zero. Ballot -> wave-uniform.
__device__ __forceinline__ bool detect_is32_wave(const unsigned int* w, long long nwords) {
    const int lane = threadIdx.x & 63;
    const long long i0 = 2 * lane + 1, i1 = 2 * (lane + 64) + 1;
    unsigned acc = 0;
    if (i0 < nwords) acc |= w[i0];
    if (i1 < nwords) acc |= w[i1];
    return __ballot(acc != 0u) != 0ull;
}

// load 4 consecutive edge indices (elements [off+i .. off+i+4)) from i32/i64 buffer
__device__ __forceinline__ int4 ld_e4(const void* ei, bool is32, long long off, long long i) {
    if (is32) return *reinterpret_cast<const int4*>((const int*)ei + off + i);
    const long long* p = (const long long*)ei + off + i;
    longlong2 a = *reinterpret_cast<const longlong2*>(p);
    longlong2 b = *reinterpret_cast<const longlong2*>(p + 2);
    return make_int4((int)a.x, (int)a.y, (int)b.x, (int)b.y);
}
__device__ __forceinline__ int ld_e1(const void* ei, bool is32, long long idx) {
    return is32 ? ((const int*)ei)[idx] : (int)((const long long*)ei)[idx];
}

// ---- 1: deg histogram over dst, packed u16 LDS cells ----
__global__ __launch_bounds__(512) void hist_deg_kernel(
        const void* __restrict__ ei, unsigned int* __restrict__ psD,
        long long E, long long SL, int nch) {
    __shared__ unsigned int hist[CHD / 2];
    const int tid = threadIdx.x;
    const bool is32 = detect_is32_wave((const unsigned int*)ei, 2 * E);
    const int b = blockIdx.x, c = b % nch, j = b / nch;
    const int lo = c * CHD;
    for (int i = tid; i < CHD / 2; i += 512) hist[i] = 0u;
    __syncthreads();
    const long long e0 = (long long)j * SL;
    long long e1 = e0 + SL; if (e1 > E) e1 = E; if (e1 < e0) e1 = e0;
    const long long e1v = e0 + ((e1 - e0) & ~3LL);
    for (long long i = e0 + (long long)tid * 4; i < e1v; i += 2048) {
        int4 d = ld_e4(ei, is32, E, i);
        unsigned u0 = (unsigned)(d.x - lo), u1 = (unsigned)(d.y - lo);
        unsigned u2 = (unsigned)(d.z - lo), u3 = (unsigned)(d.w - lo);
        if (u0 < CHD) atomicAdd(&hist[u0 >> 1], 1u << ((u0 & 1) * 16));
        if (u1 < CHD) atomicAdd(&hist[u1 >> 1], 1u << ((u1 & 1) * 16));
        if (u2 < CHD) atomicAdd(&hist[u2 >> 1], 1u << ((u2 & 1) * 16));
        if (u3 < CHD) atomicAdd(&hist[u3 >> 1], 1u << ((u3 & 1) * 16));
    }
    { long long it = e1v + tid;
      if (it < e1) { unsigned u = (unsigned)(ld_e1(ei, is32, E + it) - lo);
                     if (u < CHD) atomicAdd(&hist[u >> 1], 1u << ((u & 1) * 16)); } }
    __syncthreads();
    unsigned int* o = psD + (size_t)b * (CHD / 2);
    for (int w = tid; w < CHD / 2; w += 512) o[w] = hist[w];
}

// ---- 2: reduce deg partials ----
__global__ void deg_reduce_kernel(const unsigned int* __restrict__ psD,
                                  int* __restrict__ deg, long long n, int nch) {
    const long long tw = blockIdx.x * (long long)blockDim.x + threadIdx.x;
    if (tw >= (long long)nch * (CHD / 2)) return;
    const int cc = (int)(tw / (CHD / 2));
    const int w  = (int)(tw % (CHD / 2));
    unsigned s0 = 0, s1 = 0;
    for (int j = 0; j < NSLD; ++j) {
        unsigned v = psD[((size_t)j * nch + cc) * (CHD / 2) + w];
        s0 += v & 0xffffu; s1 += v >> 16;
    }
    const long long v0 = (long long)cc * CHD + 2 * w;
    if (v0 < n) deg[v0] = (int)s0;
    if (v0 + 1 < n) deg[v0 + 1] = (int)s1;
}

// ---- 3: per-edge u16 quantized weight qw[e] = round(2^15 * dinv[dst_e]) ----
__global__ __launch_bounds__(256) void qw_kernel(
        const void* __restrict__ ei, const int* __restrict__ deg,
        unsigned short* __restrict__ qw, long long E) {
    const bool is32 = detect_is32_wave((const unsigned int*)ei, 2 * E);
    const long long stride4 = (long long)gridDim.x * blockDim.x * 4;
    const long long E4 = E & ~3LL;
    for (long long i = (blockIdx.x * (long long)blockDim.x + threadIdx.x) * 4;
         i < E4; i += stride4) {
        int4 d = ld_e4(ei, is32, E, i);
        ushort4 q;
        q.x = quant_w16(deg[d.x] + 1);
        q.y = quant_w16(deg[d.y] + 1);
        q.z = quant_w16(deg[d.z] + 1);
        q.w = quant_w16(deg[d.w] + 1);
        *reinterpret_cast<ushort4*>(qw + i) = q;
    }
    const long long st1 = (long long)gridDim.x * blockDim.x;
    for (long long k = E4 + blockIdx.x * (long long)blockDim.x + threadIdx.x;
         k < E; k += st1)
        qw[k] = quant_w16(deg[ld_e1(ei, is32, E + k)] + 1);
}

// ---- 4: weighted src histogram (pure two-stream: src + qw, no gathers) ----
__global__ __launch_bounds__(512) void hist_s_kernel(
        const void* __restrict__ ei, const unsigned short* __restrict__ qw,
        unsigned int* __restrict__ psS, long long E, long long SL, int nch) {
    __shared__ unsigned int hist[CHS];
    const int tid = threadIdx.x;
    const bool is32 = detect_is32_wave((const unsigned int*)ei, 2 * E);
    const int b = blockIdx.x, c = b % nch, j = b / nch;
    const int lo = c * CHS;
    for (int i = tid; i < CHS; i += 512) hist[i] = 0u;
    __syncthreads();
    const long long e0 = (long long)j * SL;
    long long e1 = e0 + SL; if (e1 > E) e1 = E; if (e1 < e0) e1 = e0;
    const long long e1v = e0 + ((e1 - e0) & ~3LL);
    for (long long i = e0 + (long long)tid * 4; i < e1v; i += 2048) {
        int4 s = ld_e4(ei, is32, 0, i);
        ushort4 q = *reinterpret_cast<const ushort4*>(qw + i);
        unsigned u0 = (unsigned)(s.x - lo), u1 = (unsigned)(s.y - lo);
        unsigned u2 = (unsigned)(s.z - lo), u3 = (unsigned)(s.w - lo);
        if (u0 < CHS) atomicAdd(&hist[u0], (unsigned)q.x);
        if (u1 < CHS) atomicAdd(&hist[u1], (unsigned)q.y);
        if (u2 < CHS) atomicAdd(&hist[u2], (unsigned)q.z);
        if (u3 < CHS) atomicAdd(&hist[u3], (unsigned)q.w);
    }
    { long long it = e1v + tid;
      if (it < e1) { unsigned u = (unsigned)(ld_e1(ei, is32, it) - lo);
                     if (u < CHS) atomicAdd(&hist[u], (unsigned)qw[it]); } }
    __syncthreads();
    unsigned int* o = psS + (size_t)b * CHS;
    for (int w = tid; w < CHS; w += 512) o[w] = hist[w];
}

// ---- 5: reduce S partials -> coef[v] (coalesced psS reads) ----
__global__ void coef_reduce_kernel(const unsigned int* __restrict__ psS,
                                   const int* __restrict__ deg,
                                   float* __restrict__ coef, long long n, int nch) {
    const long long v = blockIdx.x * (long long)blockDim.x + threadIdx.x;
    if (v >= n) return;
    const int cc = (int)(v / CHS);
    const int u  = (int)(v % CHS);
    unsigned s = 0;
    #pragma unroll 8
    for (int jj = 0; jj < NSLS; ++jj)
        s += psS[((size_t)jj * nch + cc) * CHS + u];
    const float dg = (float)(deg[v] + 1);
    const float di = rsqrtf(dg);
    coef[v] = di * ((float)s * QINV2) + 1.0f / dg;
}

// ---- 6: t-partials P[b][k] (deterministic, no fence/counter) ----
__global__ __launch_bounds__(256) void reduce_x_kernel(
        const float* __restrict__ x, const float* __restrict__ coef,
        float* __restrict__ P, long long n) {
    __shared__ float4 sm4[256];
    const int tid = threadIdx.x;
    float4 a = make_float4(0.f, 0.f, 0.f, 0.f);
    const long long tot = n * (FD / 4);
    for (long long i = blockIdx.x * 256LL + tid; i < tot; i += (long long)RXB * 256) {
        float cf = coef[i >> 5];
        float4 xv = reinterpret_cast<const float4*>(x)[i];
        a.x += cf * xv.x; a.y += cf * xv.y; a.z += cf * xv.z; a.w += cf * xv.w;
    }
    const int lane = tid & 31, grp = tid >> 5;   // 8 groups of 32
    sm4[grp * 32 + lane] = a;
    __syncthreads();
    for (int s2 = 4; s2 > 0; s2 >>= 1) {
        if (grp < s2) {
            float4 o = sm4[(grp + s2) * 32 + lane];
            float4 m = sm4[grp * 32 + lane];
            m.x += o.x; m.y += o.y; m.z += o.z; m.w += o.w;
            sm4[grp * 32 + lane] = m;
        }
        __syncthreads();
    }
    if (tid < 32) reinterpret_cast<float4*>(P)[blockIdx.x * 32 + tid] = sm4[tid];
}

// ---- 7: fused colsum + W-matvec: out[f] = sum_j sum_k W[f,k]*P[j,k] + n*bias[f] ----
__global__ __launch_bounds__(256) void colsum_final_kernel(
        const float* __restrict__ P, const float* __restrict__ Wm,
        const float* __restrict__ bias, float* __restrict__ out, float nn) {
    __shared__ float wrow[FD];
    __shared__ float red[256];
    const int f = blockIdx.x, tid = threadIdx.x;
    if (tid < FD) wrow[tid] = Wm[f * FD + tid];
    __syncthreads();
    float part = 0.f;
    for (int j = tid; j < RXB; j += 256) {
        const float4* Pj = reinterpret_cast<const float4*>(P + (size_t)j * FD);
        #pragma unroll
        for (int k = 0; k < FD / 4; ++k) {
            float4 p = Pj[k];
            part += wrow[4 * k] * p.x + wrow[4 * k + 1] * p.y +
                    wrow[4 * k + 2] * p.z + wrow[4 * k + 3] * p.w;
        }
    }
    red[tid] = part;
    __syncthreads();
    for (int s2 = 128; s2 > 0; s2 >>= 1) {
        if (tid < s2) red[tid] += red[tid + s2];
        __syncthreads();
    }
    if (tid == 0) out[f] = red[0] + nn * bias[f];
}

// ================= fallback (R2-proven global-atomic path) =================
__global__ void deg_fb(const void* __restrict__ ei, int* __restrict__ deg, long long E) {
    const bool is32 = detect_is32_wave((const unsigned int*)ei, 2 * E);
    const long long st = (long long)gridDim.x * blockDim.x;
    long long i = blockIdx.x * (long long)blockDim.x + threadIdx.x;
    for (; i < E; i += st) atomicAdd(&deg[ld_e1(ei, is32, E + i)], 1);
}

__global__ void srcsum_fb(const void* __restrict__ ei, const int* __restrict__ deg,
                          unsigned int* __restrict__ Sq, long long E) {
    const bool is32 = detect_is32_wave((const unsigned int*)ei, 2 * E);
    const long long st = (long long)gridDim.x * blockDim.x;
    long long i = blockIdx.x * (long long)blockDim.x + threadIdx.x;
    for (; i < E; i += st)
        atomicAdd(&Sq[ld_e1(ei, is32, i)], quant_w(deg[ld_e1(ei, is32, E + i)] + 1));
}

__global__ void coef_fb(unsigned int* __restrict__ Sq, const int* __restrict__ deg,
                        long long n) {
    const long long v = blockIdx.x * (long long)blockDim.x + threadIdx.x;
    if (v >= n) return;
    unsigned s = Sq[v];
    float dg = (float)(deg[v] + 1);
    float di = rsqrtf(dg);
    ((float*)Sq)[v] = di * ((float)s * QINV) + 1.0f / dg;
}

__global__ void redx_fb(const float* __restrict__ x, const float* __restrict__ coef,
                        float* __restrict__ t, long long n) {
    __shared__ float sm[FD];
    for (int f = threadIdx.x; f < FD; f += blockDim.x) sm[f] = 0.f;
    __syncthreads();
    const long long tot = n * (FD / 4);
    const long long st = (long long)gridDim.x * blockDim.x;
    const int lane = threadIdx.x & 31;
    float4 a = make_float4(0.f, 0.f, 0.f, 0.f);
    for (long long i = blockIdx.x * (long long)blockDim.x + threadIdx.x; i < tot; i += st) {
        float cf = coef[i >> 5];
        float4 xv = reinterpret_cast<const float4*>(x)[i];
        a.x += cf * xv.x; a.y += cf * xv.y; a.z += cf * xv.z; a.w += cf * xv.w;
    }
    atomicAdd(&sm[lane * 4 + 0], a.x);
    atomicAdd(&sm[lane * 4 + 1], a.y);
    atomicAdd(&sm[lane * 4 + 2], a.z);
    atomicAdd(&sm[lane * 4 + 3], a.w);
    __syncthreads();
    for (int f = threadIdx.x; f < FD; f += blockDim.x) atomicAdd(&t[f], sm[f]);
}

__global__ void final_fb(const float* __restrict__ Wm, const float* __restrict__ bias,
                         const float* __restrict__ t, float* __restrict__ out, float nn) {
    __shared__ float ts[FD];
    int f = threadIdx.x;
    if (f < FD) ts[f] = t[f];
    __syncthreads();
    if (f < FD) {
        float a0 = 0.f;
        #pragma unroll 16
        for (int k = 0; k < FD; ++k) a0 += Wm[f * FD + k] * ts[k];
        out[f] = a0 + nn * bias[f];
    }
}

// ==============================================================================
extern "C" void kernel_launch(void* const* d_in, const int* in_sizes, int n_in,
                              void* d_out, int out_size, void* d_ws, size_t ws_size,
                              hipStream_t stream) {
    const float* x    = (const float*)d_in[0];
    const float* W    = (const float*)d_in[1];
    const float* bias = (const float*)d_in[2];
    const void*  ei   = d_in[3];
    float* out = (float*)d_out;
    const long long n = in_sizes[0] / FD;            // 100000
    const long long E = (long long)in_sizes[3] / 2;  // 1600000

    const int NCHD = (int)((n + CHD - 1) / CHD);     // 4
    const int NCHS = (int)((n + CHS - 1) / CHS);     // 7
    const long long SLD = ((E + NSLD - 1) / NSLD + 3) & ~3LL;   // 25000
    const long long SLS = ((E + NSLS - 1) / NSLS + 3) & ~3LL;   // 25000

    char* ws = (char*)d_ws;
    size_t off = 0;
    auto take = [&](size_t bytes) { size_t r = off; off += (bytes + 255) & ~(size_t)255; return r; };
    unsigned int*   psD  = (unsigned int*)(ws + take((size_t)NCHD * NSLD * (CHD / 2) * 4));
    unsigned int*   psS  = (unsigned int*)(ws + take((size_t)NCHS * NSLS * CHS * 4));
    int*            deg  = (int*)(ws + take((size_t)n * 4));
    float*          coef = (float*)(ws + take((size_t)n * 4));
    unsigned short* qw   = (unsigned short*)(ws + take((size_t)E * 2));
    float*          P    = (float*)(ws + take((size_t)RXB * FD * 4));
    const size_t need = off;

    const bool main_ok = (ws_size >= need) && ((E & 3) == 0) && (E >= 512) &&
                         (SLD < 65536);

    if (main_ok) {
        hist_deg_kernel<<<NCHD * NSLD, 512, 0, stream>>>(ei, psD, E, SLD, NCHD);
        {
            long long nw = (long long)NCHD * (CHD / 2);
            deg_reduce_kernel<<<(int)((nw + 255) / 256), 256, 0, stream>>>(psD, deg, n, NCHD);
        }
        qw_kernel<<<1024, 256, 0, stream>>>(ei, deg, qw, E);
        hist_s_kernel<<<NCHS * NSLS, 512, 0, stream>>>(ei, qw, psS, E, SLS, NCHS);
        coef_reduce_kernel<<<(int)((n + 255) / 256), 256, 0, stream>>>(psS, deg, coef, n, NCHS);
        reduce_x_kernel<<<RXB, 256, 0, stream>>>(x, coef, P, n);
        colsum_final_kernel<<<FD, 256, 0, stream>>>(P, W, bias, out, (float)n);
    } else {
        int*          degF = (int*)ws;
        unsigned int* Sq   = (unsigned int*)(ws + (size_t)n * 4);
        float*        tF   = (float*)(ws + (size_t)n * 8);
        hipMemsetAsync(ws, 0, (size_t)n * 8 + 512, stream);
        deg_fb<<<1600, 256, 0, stream>>>(ei, degF, E);
        srcsum_fb<<<1600, 256, 0, stream>>>(ei, degF, Sq, E);
        coef_fb<<<(int)((n + 255) / 256), 256, 0, stream>>>(Sq, degF, n);
        redx_fb<<<2048, 256, 0, stream>>>(x, (const float*)Sq, tF, n);
        final_fb<<<1, FD, 0, stream>>>(W, bias, tF, out, (float)n);
    }
}

// Round 11
// 73.266 us; speedup vs baseline: 3.3946x; 1.0616x over previous
//
#include <hip/hip_runtime.h>

#define FD 128
// deg pass: packed u16 cells, 2 nodes/word, 64 KB LDS
#define CHD 32768
#define NSLD 64
// S pass: u32 cells, 64 KB LDS
#define CHS 16384
#define NSLS 32
#define RXB 512               // reduce_x blocks
#define QSCALE 16777216.0f    // 2^24 (fallback path)
#define QINV   5.9604644775390625e-8f
#define QS14   16384.0f       // 2^14 (packed qw path)
#define QI14   6.103515625e-5f
#define SRCMASK 0x1FFFFu      // low 17 bits = src id

__device__ __forceinline__ unsigned quant_w(int dp1) {
    return (unsigned)(rsqrtf((float)dp1) * QSCALE + 0.5f);
}
__device__ __forceinline__ unsigned quant_w14(int dp1) {
    return (unsigned)(rsqrtf((float)dp1) * QS14 + 0.5f);   // <= 16384, 15 bits
}

// Wave-level dtype probe: sample up to 128 odd u32 words. int64 => high halves
// all zero; int32 => random node ids, nonzero w.h.p. Ballot -> wave-uniform.
__device__ __forceinline__ bool detect_is32_wave(const unsigned int* w, long long nwords) {
    const int lane = threadIdx.x & 63;
    const long long i0 = 2 * lane + 1, i1 = 2 * (lane + 64) + 1;
    unsigned acc = 0;
    if (i0 < nwords) acc |= w[i0];
    if (i1 < nwords) acc |= w[i1];
    return __ballot(acc != 0u) != 0ull;
}

// load 4 consecutive edge indices (elements [off+i .. off+i+4)) from i32/i64 buffer
__device__ __forceinline__ int4 ld_e4(const void* ei, bool is32, long long off, long long i) {
    if (is32) return *reinterpret_cast<const int4*>((const int*)ei + off + i);
    const long long* p = (const long long*)ei + off + i;
    longlong2 a = *reinterpret_cast<const longlong2*>(p);
    longlong2 b = *reinterpret_cast<const longlong2*>(p + 2);
    return make_int4((int)a.x, (int)a.y, (int)b.x, (int)b.y);
}
__device__ __forceinline__ int ld_e1(const void* ei, bool is32, long long idx) {
    return is32 ? ((const int*)ei)[idx] : (int)((const long long*)ei)[idx];
}

// ---- 1: deg histogram over dst, packed u16 LDS cells ----
__global__ __launch_bounds__(512) void hist_deg_kernel(
        const void* __restrict__ ei, unsigned int* __restrict__ psD,
        long long E, long long SL, int nch) {
    __shared__ unsigned int hist[CHD / 2];
    const int tid = threadIdx.x;
    const bool is32 = detect_is32_wave((const unsigned int*)ei, 2 * E);
    const int b = blockIdx.x, c = b % nch, j = b / nch;
    const int lo = c * CHD;
    for (int i = tid; i < CHD / 2; i += 512) hist[i] = 0u;
    __syncthreads();
    const long long e0 = (long long)j * SL;
    long long e1 = e0 + SL; if (e1 > E) e1 = E; if (e1 < e0) e1 = e0;
    const long long e1v = e0 + ((e1 - e0) & ~3LL);
    for (long long i = e0 + (long long)tid * 4; i < e1v; i += 2048) {
        int4 d = ld_e4(ei, is32, E, i);
        unsigned u0 = (unsigned)(d.x - lo), u1 = (unsigned)(d.y - lo);
        unsigned u2 = (unsigned)(d.z - lo), u3 = (unsigned)(d.w - lo);
        if (u0 < CHD) atomicAdd(&hist[u0 >> 1], 1u << ((u0 & 1) * 16));
        if (u1 < CHD) atomicAdd(&hist[u1 >> 1], 1u << ((u1 & 1) * 16));
        if (u2 < CHD) atomicAdd(&hist[u2 >> 1], 1u << ((u2 & 1) * 16));
        if (u3 < CHD) atomicAdd(&hist[u3 >> 1], 1u << ((u3 & 1) * 16));
    }
    { long long it = e1v + tid;
      if (it < e1) { unsigned u = (unsigned)(ld_e1(ei, is32, E + it) - lo);
                     if (u < CHD) atomicAdd(&hist[u >> 1], 1u << ((u & 1) * 16)); } }
    __syncthreads();
    unsigned int* o = psD + (size_t)b * (CHD / 2);
    for (int w = tid; w < CHD / 2; w += 512) o[w] = hist[w];
}

// ---- 2: reduce deg partials ----
__global__ void deg_reduce_kernel(const unsigned int* __restrict__ psD,
                                  int* __restrict__ deg, long long n, int nch) {
    const long long tw = blockIdx.x * (long long)blockDim.x + threadIdx.x;
    if (tw >= (long long)nch * (CHD / 2)) return;
    const int cc = (int)(tw / (CHD / 2));
    const int w  = (int)(tw % (CHD / 2));
    unsigned s0 = 0, s1 = 0;
    for (int j = 0; j < NSLD; ++j) {
        unsigned v = psD[((size_t)j * nch + cc) * (CHD / 2) + w];
        s0 += v & 0xffffu; s1 += v >> 16;
    }
    const long long v0 = (long long)cc * CHD + 2 * w;
    if (v0 < n) deg[v0] = (int)s0;
    if (v0 + 1 < n) deg[v0 + 1] = (int)s1;
}

// ---- 3: pack (qw<<17 | src) per edge; qw = round(2^14 * dinv[dst]) ----
__global__ __launch_bounds__(256) void qwpack_kernel(
        const void* __restrict__ ei, const int* __restrict__ deg,
        unsigned int* __restrict__ qp, long long E) {
    const bool is32 = detect_is32_wave((const unsigned int*)ei, 2 * E);
    const long long stride4 = (long long)gridDim.x * blockDim.x * 4;
    const long long E4 = E & ~3LL;
    for (long long i = (blockIdx.x * (long long)blockDim.x + threadIdx.x) * 4;
         i < E4; i += stride4) {
        int4 s = ld_e4(ei, is32, 0, i);
        int4 d = ld_e4(ei, is32, E, i);
        uint4 q;
        q.x = (quant_w14(deg[d.x] + 1) << 17) | (unsigned)s.x;
        q.y = (quant_w14(deg[d.y] + 1) << 17) | (unsigned)s.y;
        q.z = (quant_w14(deg[d.z] + 1) << 17) | (unsigned)s.z;
        q.w = (quant_w14(deg[d.w] + 1) << 17) | (unsigned)s.w;
        *reinterpret_cast<uint4*>(qp + i) = q;
    }
    const long long st1 = (long long)gridDim.x * blockDim.x;
    for (long long k = E4 + blockIdx.x * (long long)blockDim.x + threadIdx.x;
         k < E; k += st1)
        qp[k] = (quant_w14(deg[ld_e1(ei, is32, E + k)] + 1) << 17) |
                (unsigned)ld_e1(ei, is32, k);
}

// ---- 4: weighted src histogram over single packed stream ----
__global__ __launch_bounds__(512) void hist_s_kernel(
        const unsigned int* __restrict__ qp, unsigned int* __restrict__ psS,
        long long E, long long SL, int nch) {
    __shared__ unsigned int hist[CHS];
    const int tid = threadIdx.x;
    const int b = blockIdx.x, c = b % nch, j = b / nch;
    const int lo = c * CHS;
    for (int i = tid; i < CHS; i += 512) hist[i] = 0u;
    __syncthreads();
    const long long e0 = (long long)j * SL;
    long long e1 = e0 + SL; if (e1 > E) e1 = E; if (e1 < e0) e1 = e0;
    const long long e1v = e0 + ((e1 - e0) & ~3LL);
    for (long long i = e0 + (long long)tid * 4; i < e1v; i += 2048) {
        uint4 p = *reinterpret_cast<const uint4*>(qp + i);
        unsigned u0 = (p.x & SRCMASK) - lo, u1 = (p.y & SRCMASK) - lo;
        unsigned u2 = (p.z & SRCMASK) - lo, u3 = (p.w & SRCMASK) - lo;
        if (u0 < CHS) atomicAdd(&hist[u0], p.x >> 17);
        if (u1 < CHS) atomicAdd(&hist[u1], p.y >> 17);
        if (u2 < CHS) atomicAdd(&hist[u2], p.z >> 17);
        if (u3 < CHS) atomicAdd(&hist[u3], p.w >> 17);
    }
    { long long it = e1v + tid;
      if (it < e1) { unsigned p = qp[it];
                     unsigned u = (p & SRCMASK) - lo;
                     if (u < CHS) atomicAdd(&hist[u], p >> 17); } }
    __syncthreads();
    unsigned int* o = psS + (size_t)b * CHS;
    for (int w = tid; w < CHS; w += 512) o[w] = hist[w];
}

// ---- 5: merged coef + x reduction. Block b owns node range [b*n/RXB,(b+1)*n/RXB):
//         phase 1 computes coefs into LDS (coalesced psS reads), phase 2 streams x. ----
__global__ __launch_bounds__(256) void reduce_x_coef_kernel(
        const float* __restrict__ x, const int* __restrict__ deg,
        const unsigned int* __restrict__ psS, float* __restrict__ P,
        long long n, int nch) {
    __shared__ float lcoef[1024];
    __shared__ float4 sm4[256];
    const int tid = threadIdx.x;
    const long long vlo = (long long)blockIdx.x * n / RXB;
    const long long vhi = ((long long)blockIdx.x + 1) * n / RXB;
    const int nv = (int)(vhi - vlo);
    for (int t = tid; t < nv; t += 256) {
        const long long v = vlo + t;
        const int cc = (int)(v / CHS);
        const int u  = (int)(v % CHS);
        unsigned s = 0;
        #pragma unroll 8
        for (int jj = 0; jj < NSLS; ++jj)
            s += psS[((size_t)jj * nch + cc) * CHS + u];
        const float dg = (float)(deg[v] + 1);
        const float di = rsqrtf(dg);
        lcoef[t] = di * ((float)s * QI14) + 1.0f / dg;
    }
    __syncthreads();
    float4 a = make_float4(0.f, 0.f, 0.f, 0.f);
    const long long i0 = vlo * (FD / 4), i1 = vhi * (FD / 4);
    for (long long i = i0 + tid; i < i1; i += 256) {
        const float cf = lcoef[(int)((i >> 5) - vlo)];
        const float4 xv = reinterpret_cast<const float4*>(x)[i];
        a.x += cf * xv.x; a.y += cf * xv.y; a.z += cf * xv.z; a.w += cf * xv.w;
    }
    const int lane = tid & 31, grp = tid >> 5;   // 8 groups of 32
    sm4[grp * 32 + lane] = a;
    __syncthreads();
    for (int s2 = 4; s2 > 0; s2 >>= 1) {
        if (grp < s2) {
            float4 o = sm4[(grp + s2) * 32 + lane];
            float4 m = sm4[grp * 32 + lane];
            m.x += o.x; m.y += o.y; m.z += o.z; m.w += o.w;
            sm4[grp * 32 + lane] = m;
        }
        __syncthreads();
    }
    if (tid < 32) reinterpret_cast<float4*>(P)[blockIdx.x * 32 + tid] = sm4[tid];
}

// ---- 6: fused colsum + W-matvec: out[f] = sum_j sum_k W[f,k]*P[j,k] + n*bias[f] ----
__global__ __launch_bounds__(256) void colsum_final_kernel(
        const float* __restrict__ P, const float* __restrict__ Wm,
        const float* __restrict__ bias, float* __restrict__ out, float nn) {
    __shared__ float wrow[FD];
    __shared__ float red[256];
    const int f = blockIdx.x, tid = threadIdx.x;
    if (tid < FD) wrow[tid] = Wm[f * FD + tid];
    __syncthreads();
    float part = 0.f;
    for (int j = tid; j < RXB; j += 256) {
        const float4* Pj = reinterpret_cast<const float4*>(P + (size_t)j * FD);
        #pragma unroll
        for (int k = 0; k < FD / 4; ++k) {
            float4 p = Pj[k];
            part += wrow[4 * k] * p.x + wrow[4 * k + 1] * p.y +
                    wrow[4 * k + 2] * p.z + wrow[4 * k + 3] * p.w;
        }
    }
    red[tid] = part;
    __syncthreads();
    for (int s2 = 128; s2 > 0; s2 >>= 1) {
        if (tid < s2) red[tid] += red[tid + s2];
        __syncthreads();
    }
    if (tid == 0) out[f] = red[0] + nn * bias[f];
}

// ================= fallback (R2-proven global-atomic path) =================
__global__ void deg_fb(const void* __restrict__ ei, int* __restrict__ deg, long long E) {
    const bool is32 = detect_is32_wave((const unsigned int*)ei, 2 * E);
    const long long st = (long long)gridDim.x * blockDim.x;
    long long i = blockIdx.x * (long long)blockDim.x + threadIdx.x;
    for (; i < E; i += st) atomicAdd(&deg[ld_e1(ei, is32, E + i)], 1);
}

__global__ void srcsum_fb(const void* __restrict__ ei, const int* __restrict__ deg,
                          unsigned int* __restrict__ Sq, long long E) {
    const bool is32 = detect_is32_wave((const unsigned int*)ei, 2 * E);
    const long long st = (long long)gridDim.x * blockDim.x;
    long long i = blockIdx.x * (long long)blockDim.x + threadIdx.x;
    for (; i < E; i += st)
        atomicAdd(&Sq[ld_e1(ei, is32, i)], quant_w(deg[ld_e1(ei, is32, E + i)] + 1));
}

__global__ void coef_fb(unsigned int* __restrict__ Sq, const int* __restrict__ deg,
                        long long n) {
    const long long v = blockIdx.x * (long long)blockDim.x + threadIdx.x;
    if (v >= n) return;
    unsigned s = Sq[v];
    float dg = (float)(deg[v] + 1);
    float di = rsqrtf(dg);
    ((float*)Sq)[v] = di * ((float)s * QINV) + 1.0f / dg;
}

__global__ void redx_fb(const float* __restrict__ x, const float* __restrict__ coef,
                        float* __restrict__ t, long long n) {
    __shared__ float sm[FD];
    for (int f = threadIdx.x; f < FD; f += blockDim.x) sm[f] = 0.f;
    __syncthreads();
    const long long tot = n * (FD / 4);
    const long long st = (long long)gridDim.x * blockDim.x;
    const int lane = threadIdx.x & 31;
    float4 a = make_float4(0.f, 0.f, 0.f, 0.f);
    for (long long i = blockIdx.x * (long long)blockDim.x + threadIdx.x; i < tot; i += st) {
        float cf = coef[i >> 5];
        float4 xv = reinterpret_cast<const float4*>(x)[i];
        a.x += cf * xv.x; a.y += cf * xv.y; a.z += cf * xv.z; a.w += cf * xv.w;
    }
    atomicAdd(&sm[lane * 4 + 0], a.x);
    atomicAdd(&sm[lane * 4 + 1], a.y);
    atomicAdd(&sm[lane * 4 + 2], a.z);
    atomicAdd(&sm[lane * 4 + 3], a.w);
    __syncthreads();
    for (int f = threadIdx.x; f < FD; f += blockDim.x) atomicAdd(&t[f], sm[f]);
}

__global__ void final_fb(const float* __restrict__ Wm, const float* __restrict__ bias,
                         const float* __restrict__ t, float* __restrict__ out, float nn) {
    __shared__ float ts[FD];
    int f = threadIdx.x;
    if (f < FD) ts[f] = t[f];
    __syncthreads();
    if (f < FD) {
        float a0 = 0.f;
        #pragma unroll 16
        for (int k = 0; k < FD; ++k) a0 += Wm[f * FD + k] * ts[k];
        out[f] = a0 + nn * bias[f];
    }
}

// ==============================================================================
extern "C" void kernel_launch(void* const* d_in, const int* in_sizes, int n_in,
                              void* d_out, int out_size, void* d_ws, size_t ws_size,
                              hipStream_t stream) {
    const float* x    = (const float*)d_in[0];
    const float* W    = (const float*)d_in[1];
    const float* bias = (const float*)d_in[2];
    const void*  ei   = d_in[3];
    float* out = (float*)d_out;
    const long long n = in_sizes[0] / FD;            // 100000
    const long long E = (long long)in_sizes[3] / 2;  // 1600000

    const int NCHD = (int)((n + CHD - 1) / CHD);     // 4
    const int NCHS = (int)((n + CHS - 1) / CHS);     // 7
    const long long SLD = ((E + NSLD - 1) / NSLD + 3) & ~3LL;   // 25000
    const long long SLS = ((E + NSLS - 1) / NSLS + 3) & ~3LL;   // 50000

    char* ws = (char*)d_ws;
    size_t off = 0;
    auto take = [&](size_t bytes) { size_t r = off; off += (bytes + 255) & ~(size_t)255; return r; };
    unsigned int* psD = (unsigned int*)(ws + take((size_t)NCHD * NSLD * (CHD / 2) * 4));
    unsigned int* psS = (unsigned int*)(ws + take((size_t)NCHS * NSLS * CHS * 4));
    int*          deg = (int*)(ws + take((size_t)n * 4));
    unsigned int* qp  = (unsigned int*)(ws + take((size_t)E * 4));
    float*        P   = (float*)(ws + take((size_t)RXB * FD * 4));
    const size_t need = off;

    const bool main_ok = (ws_size >= need) && ((E & 3) == 0) && (E >= 512) &&
                         (SLD < 65536) && (n <= (1LL << 17)) &&
                         (n <= (long long)RXB * 1024);

    if (main_ok) {
        hist_deg_kernel<<<NCHD * NSLD, 512, 0, stream>>>(ei, psD, E, SLD, NCHD);
        {
            long long nw = (long long)NCHD * (CHD / 2);
            deg_reduce_kernel<<<(int)((nw + 255) / 256), 256, 0, stream>>>(psD, deg, n, NCHD);
        }
        qwpack_kernel<<<1024, 256, 0, stream>>>(ei, deg, qp, E);
        hist_s_kernel<<<NCHS * NSLS, 512, 0, stream>>>(qp, psS, E, SLS, NCHS);
        reduce_x_coef_kernel<<<RXB, 256, 0, stream>>>(x, deg, psS, P, n, NCHS);
        colsum_final_kernel<<<FD, 256, 0, stream>>>(P, W, bias, out, (float)n);
    } else {
        int*          degF = (int*)ws;
        unsigned int* Sq   = (unsigned int*)(ws + (size_t)n * 4);
        float*        tF   = (float*)(ws + (size_t)n * 8);
        hipMemsetAsync(ws, 0, (size_t)n * 8 + 512, stream);
        deg_fb<<<1600, 256, 0, stream>>>(ei, degF, E);
        srcsum_fb<<<1600, 256, 0, stream>>>(ei, degF, Sq, E);
        coef_fb<<<(int)((n + 255) / 256), 256, 0, stream>>>(Sq, degF, n);
        redx_fb<<<2048, 256, 0, stream>>>(x, (const float*)Sq, tF, n);
        final_fb<<<1, FD, 0, stream>>>(W, bias, tF, out, (float)n);
    }
}